// Round 8
// baseline (520.324 us; speedup 1.0000x reference)
//
#include <hip/hip_runtime.h>

#define H 20
#define NODE 480
#define BATCH 16384
#define BLK 256
#define GPT 16            // one full 64B line per lane (16 nodes x 4B) in AND out
#define NGRP (NODE / GPT) // 30
#define PAD 20            // LDS row stride (floats): 80B keeps 16B alignment for b128

typedef float v2f __attribute__((ext_vector_type(2)));
typedef float v4f __attribute__((ext_vector_type(4)));

// tanh(x) = 1 - 2/(e^{2x}+1); 2 trans + 3 VALU, saturates correctly at +-inf.
__device__ __forceinline__ float fast_tanh(float x) {
    float t = __builtin_amdgcn_exp2f(x * 2.8853900817779268f); // e^{2x}
    return 1.0f - 2.0f * __builtin_amdgcn_rcpf(t + 1.0f);
}
__device__ __forceinline__ v2f tanh2(v2f v) {
    v2f r; r.x = fast_tanh(v.x); r.y = fast_tanh(v.y); return r;
}

// R6 lesson: GPT=4 direct v4f loads = 1/4 line use -> FETCH 129MB. Now each
// lane owns a full line; IO staged through LDS with exact-coalesced passes.
// gi loop rolled (16 unrolled MLPs ~ 100KB I$); weight ptrs advance uniformly
// so all weight reads stay wave-uniform s_loads. Inner arrays static-indexed.
__global__ __attribute__((amdgpu_flat_work_group_size(BLK, BLK),
                          amdgpu_waves_per_eu(1)))
void mlp480_fused(const float* __restrict__ inputs,
    const float* __restrict__ W1, const float* __restrict__ b1,
    const float* __restrict__ W2, const float* __restrict__ b2,
    const float* __restrict__ W3, const float* __restrict__ b3,
    const float* __restrict__ W4, const float* __restrict__ b4,
    float* __restrict__ out)
{
    __shared__ float xio[BLK][PAD];   // 20 KB; x on entry, o on exit (same slots)

    const int g0 = blockIdx.x * GPT;
    const int b0 = blockIdx.y * BLK;
    const int tid = threadIdx.x;

    // stage-in: 4 passes x 256 lanes x 16B; groups of 4 lanes cover whole lines
#pragma unroll
    for (int p = 0; p < 4; ++p) {
        const int idx = p * BLK + tid;
        const int r = idx >> 2, c4 = idx & 3;
        const v4f v = *(const v4f*)(inputs + (size_t)(b0 + r) * NODE + g0 + c4 * 4);
        *(v4f*)&xio[r][c4 * 4] = v;
    }
    __syncthreads();

    // running wave-uniform weight pointers (loop-carried SGPR arithmetic)
    const float* wp1 = W1 + (size_t)g0 * H;
    const float* bp1 = b1 + (size_t)g0 * H;
    const float* wp2 = W2 + (size_t)g0 * H * H;
    const float* bp2 = b2 + (size_t)g0 * H;
    const float* wp3 = W3 + (size_t)g0 * H * H;
    const float* bp3 = b3 + (size_t)g0 * H;
    const float* wp4 = W4 + (size_t)g0 * H;
    const float* bp4 = b4 + g0;

#pragma unroll 1
    for (int gi = 0; gi < GPT; ++gi) {
        const float x = xio[tid][gi];
        const v2f x2 = {x, x};
        v2f h2[10], a2[10];

        // Layer 1
        const v2f* w1v = (const v2f*)wp1;
        const v2f* b1v = (const v2f*)bp1;
#pragma unroll
        for (int j = 0; j < 10; ++j)
            h2[j] = tanh2(x2 * w1v[j] + b1v[j]);

        // Layer 2: k-outer, contiguous wave-uniform rows
        const v2f* b2v = (const v2f*)bp2;
#pragma unroll
        for (int l = 0; l < 10; ++l) a2[l] = b2v[l];
#pragma unroll
        for (int k = 0; k < H; ++k) {
            const float hk = (k & 1) ? h2[k >> 1].y : h2[k >> 1].x;
            const v2f hk2 = {hk, hk};
            const v2f* row = (const v2f*)(wp2 + k * H);
#pragma unroll
            for (int l = 0; l < 10; ++l) a2[l] = hk2 * row[l] + a2[l];
        }
#pragma unroll
        for (int l = 0; l < 10; ++l) h2[l] = tanh2(a2[l]);

        // Layer 3
        const v2f* b3v = (const v2f*)bp3;
#pragma unroll
        for (int l = 0; l < 10; ++l) a2[l] = b3v[l];
#pragma unroll
        for (int k = 0; k < H; ++k) {
            const float hk = (k & 1) ? h2[k >> 1].y : h2[k >> 1].x;
            const v2f hk2 = {hk, hk};
            const v2f* row = (const v2f*)(wp3 + k * H);
#pragma unroll
            for (int l = 0; l < 10; ++l) a2[l] = hk2 * row[l] + a2[l];
        }
#pragma unroll
        for (int l = 0; l < 10; ++l) h2[l] = tanh2(a2[l]);

        // Layer 4
        const v2f* w4v = (const v2f*)wp4;
        v2f s2 = {bp4[gi], 0.0f};
#pragma unroll
        for (int k = 0; k < 10; ++k) s2 = h2[k] * w4v[k] + s2;
        xio[tid][gi] = s2.x + s2.y;

        wp1 += H; bp1 += H; wp2 += H * H; bp2 += H;
        wp3 += H * H; bp3 += H; wp4 += H;
    }
    __syncthreads();

    // stage-out: exact mirror of stage-in
#pragma unroll
    for (int p = 0; p < 4; ++p) {
        const int idx = p * BLK + tid;
        const int r = idx >> 2, c4 = idx & 3;
        *(v4f*)(out + (size_t)(b0 + r) * NODE + g0 + c4 * 4) = *(const v4f*)&xio[r][c4 * 4];
    }
}

extern "C" void kernel_launch(void* const* d_in, const int* in_sizes, int n_in,
                              void* d_out, int out_size, void* d_ws, size_t ws_size,
                              hipStream_t stream) {
    const float* inputs = (const float*)d_in[0];
    const float* W1 = (const float*)d_in[1];
    const float* b1 = (const float*)d_in[2];
    const float* W2 = (const float*)d_in[3];
    const float* b2 = (const float*)d_in[4];
    const float* W3 = (const float*)d_in[5];
    const float* b3 = (const float*)d_in[6];
    const float* W4 = (const float*)d_in[7];
    const float* b4 = (const float*)d_in[8];
    float* out = (float*)d_out;

    dim3 grid(NGRP, BATCH / BLK);   // (30, 64) = 1920 blocks
    mlp480_fused<<<grid, BLK, 0, stream>>>(inputs, W1, b1, W2, b2,
                                           W3, b3, W4, b4, out);
}

// Round 9
// 316.829 us; speedup vs baseline: 1.6423x; 1.6423x over previous
//
#include <hip/hip_runtime.h>

#define H 20
#define NODE 480
#define BATCH 16384
#define BLK 256

typedef float v2f __attribute__((ext_vector_type(2)));

// ---- variant A: exp-based tanh: 4 VALU + 4 trans per pair ----
__device__ __forceinline__ float fast_tanh(float x) {
    float t = __builtin_amdgcn_exp2f(x * 2.8853900817779268f); // e^{2x}
    return 1.0f - 2.0f * __builtin_amdgcn_rcpf(t + 1.0f);
}
__device__ __forceinline__ v2f tanh2_exp(v2f v) {
    v2f r; r.x = fast_tanh(v.x); r.y = fast_tanh(v.y); return r;
}

// ---- variant B: Eigen ptanh rational 13/6 (no exp) + paired rcp:
//      ~17 VALU + 1 trans per pair ----
__device__ __forceinline__ v2f tanh2_rat(v2f v) {
    const float C = 7.90531110763549805f;
    v2f x;
    x.x = fminf(fmaxf(v.x, -C), C);   // compiler: v_med3_f32
    x.y = fminf(fmaxf(v.y, -C), C);
    const v2f u = x * x;
    const v2f a13 = {-2.76076847742355e-16f, -2.76076847742355e-16f};
    const v2f a11 = { 2.00018790482477e-13f,  2.00018790482477e-13f};
    const v2f a9  = {-8.60467152213735e-11f, -8.60467152213735e-11f};
    const v2f a7  = { 5.12229709037114e-08f,  5.12229709037114e-08f};
    const v2f a5  = { 1.48572235717979e-05f,  1.48572235717979e-05f};
    const v2f a3  = { 6.37261928875436e-04f,  6.37261928875436e-04f};
    const v2f a1  = { 4.89352455891786e-03f,  4.89352455891786e-03f};
    const v2f b6  = { 1.19825839466702e-06f,  1.19825839466702e-06f};
    const v2f b4  = { 1.18534705686654e-04f,  1.18534705686654e-04f};
    const v2f b2  = { 2.26843463243900e-03f,  2.26843463243900e-03f};
    const v2f b0  = { 4.89352518554385e-03f,  4.89352518554385e-03f};
    v2f p = u * a13 + a11;
    p = u * p + a9;  p = u * p + a7;  p = u * p + a5;
    p = u * p + a3;  p = u * p + a1;  p = p * x;
    v2f q = u * b6 + b4;
    q = u * q + b2;  q = u * q + b0;
    // paired reciprocal: one v_rcp for two divisions
    const float rr = __builtin_amdgcn_rcpf(q.x * q.y);
    const v2f inv = {rr * q.y, rr * q.x};
    return p * inv;
}

template <int TANH>
__device__ __forceinline__ v2f tanh2(v2f v) {
    if constexpr (TANH == 0) return tanh2_exp(v);
    else                     return tanh2_rat(v);
}

// ---------------- transpose kernels (unchanged from R4) ----------------
__global__ __launch_bounds__(256) void transpose_in(const float* __restrict__ src,
                                                    float* __restrict__ dst) {
    __shared__ float t[32][33];
    const int gT = blockIdx.x * 32, bT = blockIdx.y * 32;
    const int tx = threadIdx.x, ty = threadIdx.y;
#pragma unroll
    for (int j = 0; j < 32; j += 8)
        t[ty + j][tx] = src[(bT + ty + j) * NODE + gT + tx];
    __syncthreads();
#pragma unroll
    for (int j = 0; j < 32; j += 8)
        dst[(gT + ty + j) * BATCH + bT + tx] = t[tx][ty + j];
}

__global__ __launch_bounds__(256) void transpose_out(const float* __restrict__ src,
                                                     float* __restrict__ dst) {
    __shared__ float t[32][33];
    const int gT = blockIdx.x * 32, bT = blockIdx.y * 32;
    const int tx = threadIdx.x, ty = threadIdx.y;
#pragma unroll
    for (int j = 0; j < 32; j += 8)
        t[ty + j][tx] = src[(gT + ty + j) * BATCH + bT + tx];
    __syncthreads();
#pragma unroll
    for (int j = 0; j < 32; j += 8)
        dst[(bT + ty + j) * NODE + gT + tx] = t[tx][ty + j];
}

// ---------------- main kernel: R4 structure, templated tanh ----------------
template <int TANH>
__global__ __launch_bounds__(BLK, 1) void mlp480_kernel(
    const float* __restrict__ inputs,
    const float* __restrict__ W1, const float* __restrict__ b1,
    const float* __restrict__ W2, const float* __restrict__ b2,
    const float* __restrict__ W3, const float* __restrict__ b3,
    const float* __restrict__ W4, const float* __restrict__ b4,
    float* __restrict__ out, int by_base)
{
    const int g = blockIdx.x;
    const int b = (by_base + blockIdx.y) * BLK + threadIdx.x;

    const v2f* __restrict__ w1v = (const v2f*)(W1 + g * H);
    const v2f* __restrict__ b1v = (const v2f*)(b1 + g * H);
    const v2f* __restrict__ b2v = (const v2f*)(b2 + g * H);
    const v2f* __restrict__ b3v = (const v2f*)(b3 + g * H);
    const v2f* __restrict__ w4v = (const v2f*)(W4 + g * H);
    const float* __restrict__ w2 = W2 + g * H * H;
    const float* __restrict__ w3 = W3 + g * H * H;
    const float bias4 = b4[g];

    const float x = inputs[g * BATCH + b];
    const v2f x2 = {x, x};

    v2f h2[10], a2[10];

    // Layer 1
#pragma unroll
    for (int j = 0; j < 10; ++j)
        h2[j] = tanh2<TANH>(x2 * w1v[j] + b1v[j]);

    // Layer 2
#pragma unroll
    for (int l = 0; l < 10; ++l) a2[l] = b2v[l];
#pragma unroll
    for (int k = 0; k < H; ++k) {
        const float hk = (k & 1) ? h2[k >> 1].y : h2[k >> 1].x;
        const v2f hk2 = {hk, hk};
        const v2f* __restrict__ row = (const v2f*)(w2 + k * H);
#pragma unroll
        for (int l = 0; l < 10; ++l) a2[l] = hk2 * row[l] + a2[l];
    }
#pragma unroll
    for (int l = 0; l < 10; ++l) h2[l] = tanh2<TANH>(a2[l]);

    // Layer 3
#pragma unroll
    for (int l = 0; l < 10; ++l) a2[l] = b3v[l];
#pragma unroll
    for (int k = 0; k < H; ++k) {
        const float hk = (k & 1) ? h2[k >> 1].y : h2[k >> 1].x;
        const v2f hk2 = {hk, hk};
        const v2f* __restrict__ row = (const v2f*)(w3 + k * H);
#pragma unroll
        for (int l = 0; l < 10; ++l) a2[l] = hk2 * row[l] + a2[l];
    }
#pragma unroll
    for (int l = 0; l < 10; ++l) h2[l] = tanh2<TANH>(a2[l]);

    // Layer 4
    v2f s2 = {bias4, 0.0f};
#pragma unroll
    for (int k = 0; k < 10; ++k) s2 = h2[k] * w4v[k] + s2;
    const float o = s2.x + s2.y;

    out[g * BATCH + b] = o;
}

extern "C" void kernel_launch(void* const* d_in, const int* in_sizes, int n_in,
                              void* d_out, int out_size, void* d_ws, size_t ws_size,
                              hipStream_t stream) {
    const float* inputs = (const float*)d_in[0];
    const float* W1 = (const float*)d_in[1];
    const float* b1 = (const float*)d_in[2];
    const float* W2 = (const float*)d_in[3];
    const float* b2 = (const float*)d_in[4];
    const float* W3 = (const float*)d_in[5];
    const float* b3 = (const float*)d_in[6];
    const float* W4 = (const float*)d_in[7];
    const float* b4 = (const float*)d_in[8];
    float* out = (float*)d_out;

    const size_t planeBytes = (size_t)BATCH * NODE * sizeof(float);
    float* in_t  = (float*)d_ws;
    float* out_t = (float*)((char*)d_ws + planeBytes);

    dim3 tGrid(NODE / 32, BATCH / 32), tBlk(32, 8);
    transpose_in<<<tGrid, tBlk, 0, stream>>>(inputs, in_t);

    // A/B: exp-tanh on first half of batch, rational tanh on second half.
    dim3 halfGrid(NODE, BATCH / BLK / 2);   // (480, 32)
    mlp480_kernel<0><<<halfGrid, BLK, 0, stream>>>(in_t, W1, b1, W2, b2,
                                                   W3, b3, W4, b4, out_t, 0);
    mlp480_kernel<1><<<halfGrid, BLK, 0, stream>>>(in_t, W1, b1, W2, b2,
                                                   W3, b3, W4, b4, out_t,
                                                   BATCH / BLK / 2);

    transpose_out<<<tGrid, tBlk, 0, stream>>>(out_t, out);
}